// Round 1
// baseline (439.466 us; speedup 1.0000x reference)
//
#include <hip/hip_runtime.h>
#include <hip/hip_bf16.h>

#define B_ 4
#define N_ 1024
#define NB_ 32
#define C_ 384
#define CZ_ 128
#define NSITES (B_ * N_)   // 4096
#define EPSV 1e-6f
#define PAD 40             // ushorts per LDS row (32 data + 8 pad -> 2-way-only bank aliasing)

typedef unsigned short u16;
typedef unsigned int u32;
typedef __bf16 bf16x8 __attribute__((ext_vector_type(8)));
typedef float f32x4 __attribute__((ext_vector_type(4)));

__device__ __forceinline__ u16 f2bf(float f) {
    return __builtin_bit_cast(u16, __float2bfloat16(f));
}
__device__ __forceinline__ float bfbits2f(u16 u) {
    union { float f; u32 i; } x;
    x.i = ((u32)u) << 16;
    return x.f;
}

// Transpose weights to bf16: Wts[d][c] = bf16(W_s[c][d]) (384x384), Wtz[d][z] = bf16(W_z[z][d]) (384x128)
__global__ void prep_weights(const float* __restrict__ Ws, const float* __restrict__ Wz,
                             u16* __restrict__ Wts, u16* __restrict__ Wtz) {
    int idx = blockIdx.x * 256 + threadIdx.x;
    if (idx < C_ * C_) {
        int d = idx / C_, c = idx % C_;
        Wts[idx] = f2bf(Ws[c * C_ + d]);
    } else {
        int j = idx - C_ * C_;
        if (j < C_ * CZ_) {
            int d = j / CZ_, z = j % CZ_;
            Wtz[j] = f2bf(Wz[z * C_ + d]);
        }
    }
}

// Fused: gate = z_ij@W_z (bf16 MFMA), s_proj = s_ij@W_s, msg = (s_proj - s_i)*gate*m, sum over 32
// neighbors, LayerNorm. Block = 256 thr (4 waves), 2 sites/block, wave owns a 96-col strip.
__global__ __launch_bounds__(256, 2)
void fused_msg_kernel(const float* __restrict__ s_i,
                      const float* __restrict__ s_ij,
                      const float* __restrict__ m_ij,
                      const float* __restrict__ z_ij,
                      const u16* __restrict__ Wts,
                      const u16* __restrict__ Wtz,
                      const float* __restrict__ gamma,
                      const float* __restrict__ beta,
                      float* __restrict__ out) {
    __shared__ u16 ldsW[C_ * PAD];     // 30720 B : W chunk, 384 cols x 32 k (padded)
    __shared__ u16 ldsA[64 * PAD];     // 5120 B  : A chunk, 64 rows x 32 k (padded)
    __shared__ float lds_si[2 * C_];   // center acts for 2 sites
    __shared__ float lds_m[64];        // neighbor masks for 2 sites
    __shared__ float lds_snew[2 * C_]; // pre-LN sums

    const int tid = threadIdx.x;
    const int wave = tid >> 6;
    const int lane = tid & 63;
    const int q = lane >> 4;    // quad within wave
    const int ln = lane & 15;
    const int colbase = wave * 96;

    const int site0 = blockIdx.x * 2;
    const long rowbase = (long)site0 * NB_;   // first neighbor row (of 131072)

    for (int i = tid; i < 2 * C_; i += 256)
        lds_si[i] = s_i[(long)site0 * C_ + i];
    if (tid < 64) lds_m[tid] = m_ij[rowbase + tid];

    const f32x4 ZERO = {0.f, 0.f, 0.f, 0.f};
    f32x4 acc[4][6];
    #pragma unroll
    for (int mt = 0; mt < 4; ++mt)
        #pragma unroll
        for (int nt = 0; nt < 6; ++nt)
            acc[mt][nt] = ZERO;

    // ---------------- Phase 1: gate = z_ij @ W_z  (K = 128) ----------------
    #pragma unroll 1
    for (int kc = 0; kc < CZ_; kc += 32) {
        // stage W_z chunk: 384 rows x 32 k bf16 (1536 16B-segs, 6/thread)
        int s = tid;
        #pragma unroll
        for (int i = 0; i < 6; ++i) {
            int row = s >> 2, seg = s & 3;
            uint4 v = *reinterpret_cast<const uint4*>(Wtz + row * CZ_ + kc + seg * 8);
            *reinterpret_cast<uint4*>(&ldsW[row * PAD + seg * 8]) = v;
            s += 256;
        }
        // stage A chunk: 64 rows x 32 fp32 -> bf16 (1 seg of 8/thread)
        {
            int row = tid >> 2, seg = tid & 3;
            const float* src = z_ij + (rowbase + row) * CZ_ + kc + seg * 8;
            float4 v0 = *reinterpret_cast<const float4*>(src);
            float4 v1 = *reinterpret_cast<const float4*>(src + 4);
            uint4 h;
            h.x = ((u32)f2bf(v0.y) << 16) | f2bf(v0.x);
            h.y = ((u32)f2bf(v0.w) << 16) | f2bf(v0.z);
            h.z = ((u32)f2bf(v1.y) << 16) | f2bf(v1.x);
            h.w = ((u32)f2bf(v1.w) << 16) | f2bf(v1.z);
            *reinterpret_cast<uint4*>(&ldsA[row * PAD + seg * 8]) = h;
        }
        __syncthreads();
        bf16x8 a[4];
        #pragma unroll
        for (int mt = 0; mt < 4; ++mt)
            a[mt] = *reinterpret_cast<const bf16x8*>(&ldsA[(mt * 16 + ln) * PAD + q * 8]);
        #pragma unroll
        for (int nt = 0; nt < 6; ++nt) {
            bf16x8 b = *reinterpret_cast<const bf16x8*>(&ldsW[(colbase + nt * 16 + ln) * PAD + q * 8]);
            #pragma unroll
            for (int mt = 0; mt < 4; ++mt)
                acc[mt][nt] = __builtin_amdgcn_mfma_f32_16x16x32_bf16(a[mt], b, acc[mt][nt], 0, 0, 0);
        }
        __syncthreads();
    }

    // fold mask into gate, pack to bf16 pairs, free accumulators
    u32 gateb[4][6][2];
    #pragma unroll
    for (int mt = 0; mt < 4; ++mt) {
        float m0 = lds_m[mt * 16 + q * 4 + 0];
        float m1 = lds_m[mt * 16 + q * 4 + 1];
        float m2 = lds_m[mt * 16 + q * 4 + 2];
        float m3 = lds_m[mt * 16 + q * 4 + 3];
        #pragma unroll
        for (int nt = 0; nt < 6; ++nt) {
            gateb[mt][nt][0] = ((u32)f2bf(acc[mt][nt][1] * m1) << 16) | f2bf(acc[mt][nt][0] * m0);
            gateb[mt][nt][1] = ((u32)f2bf(acc[mt][nt][3] * m3) << 16) | f2bf(acc[mt][nt][2] * m2);
            acc[mt][nt] = ZERO;
        }
    }

    // ---------------- Phase 2: s_proj = s_ij @ W_s  (K = 384) ----------------
    #pragma unroll 1
    for (int kc = 0; kc < C_; kc += 32) {
        int s = tid;
        #pragma unroll
        for (int i = 0; i < 6; ++i) {
            int row = s >> 2, seg = s & 3;
            uint4 v = *reinterpret_cast<const uint4*>(Wts + row * C_ + kc + seg * 8);
            *reinterpret_cast<uint4*>(&ldsW[row * PAD + seg * 8]) = v;
            s += 256;
        }
        {
            int row = tid >> 2, seg = tid & 3;
            const float* src = s_ij + (rowbase + row) * C_ + kc + seg * 8;
            float4 v0 = *reinterpret_cast<const float4*>(src);
            float4 v1 = *reinterpret_cast<const float4*>(src + 4);
            uint4 h;
            h.x = ((u32)f2bf(v0.y) << 16) | f2bf(v0.x);
            h.y = ((u32)f2bf(v0.w) << 16) | f2bf(v0.z);
            h.z = ((u32)f2bf(v1.y) << 16) | f2bf(v1.x);
            h.w = ((u32)f2bf(v1.w) << 16) | f2bf(v1.z);
            *reinterpret_cast<uint4*>(&ldsA[row * PAD + seg * 8]) = h;
        }
        __syncthreads();
        bf16x8 a[4];
        #pragma unroll
        for (int mt = 0; mt < 4; ++mt)
            a[mt] = *reinterpret_cast<const bf16x8*>(&ldsA[(mt * 16 + ln) * PAD + q * 8]);
        #pragma unroll
        for (int nt = 0; nt < 6; ++nt) {
            bf16x8 b = *reinterpret_cast<const bf16x8*>(&ldsW[(colbase + nt * 16 + ln) * PAD + q * 8]);
            #pragma unroll
            for (int mt = 0; mt < 4; ++mt)
                acc[mt][nt] = __builtin_amdgcn_mfma_f32_16x16x32_bf16(a[mt], b, acc[mt][nt], 0, 0, 0);
        }
        __syncthreads();
    }

    // ---------------- Epilogue: msg + neighbor reduction ----------------
    // acc tile (mt,nt): row = mt*16 + q*4 + r (neighbor index within block), col = colbase + nt*16 + ln
    #pragma unroll
    for (int site = 0; site < 2; ++site) {
        #pragma unroll
        for (int nt = 0; nt < 6; ++nt) {
            int col = colbase + nt * 16 + ln;
            float si = lds_si[site * C_ + col];
            float p = 0.f;
            #pragma unroll
            for (int mh = 0; mh < 2; ++mh) {
                int mt = site * 2 + mh;
                #pragma unroll
                for (int r = 0; r < 4; ++r) {
                    float g = bfbits2f((u16)(gateb[mt][nt][r >> 1] >> ((r & 1) * 16)));
                    p += (acc[mt][nt][r] - si) * g;
                }
            }
            // reduce across the 4 quads (rows) -> every lane holds the 16-row-tile-pair sum
            p += __shfl_xor(p, 16, 64);
            p += __shfl_xor(p, 32, 64);
            if (q == 0) lds_snew[site * C_ + col] = p;
        }
    }
    __syncthreads();

    // ---------------- LayerNorm: wave 0 -> site0, wave 1 -> site1 ----------------
    if (wave < 2) {
        const int site = wave;
        float v[6];
        float sum = 0.f, sumsq = 0.f;
        #pragma unroll
        for (int i = 0; i < 6; ++i) {
            v[i] = lds_snew[site * C_ + lane + i * 64];
            sum += v[i];
            sumsq += v[i] * v[i];
        }
        #pragma unroll
        for (int off = 32; off >= 1; off >>= 1) {
            sum += __shfl_xor(sum, off, 64);
            sumsq += __shfl_xor(sumsq, off, 64);
        }
        float mu = sum * (1.f / C_);
        float var = sumsq * (1.f / C_) - mu * mu;
        float rs = rsqrtf(var + EPSV);
        #pragma unroll
        for (int i = 0; i < 6; ++i) {
            int col = lane + i * 64;
            out[(long)(site0 + site) * C_ + col] = (v[i] - mu) * rs * gamma[col] + beta[col];
        }
    }
}

extern "C" void kernel_launch(void* const* d_in, const int* in_sizes, int n_in,
                              void* d_out, int out_size, void* d_ws, size_t ws_size,
                              hipStream_t stream) {
    (void)in_sizes; (void)n_in; (void)out_size; (void)ws_size;
    const float* s_i   = (const float*)d_in[0];
    const float* s_ij  = (const float*)d_in[1];
    const float* m_ij  = (const float*)d_in[2];
    const float* z_ij  = (const float*)d_in[3];
    const float* W_s   = (const float*)d_in[4];
    const float* W_z   = (const float*)d_in[5];
    const float* gamma = (const float*)d_in[6];
    const float* beta  = (const float*)d_in[7];
    float* out = (float*)d_out;

    u16* wts = (u16*)d_ws;             // 384*384 bf16 = 294912 B
    u16* wtz = wts + C_ * C_;          // 384*128 bf16 =  98304 B  (total 393216 B of ws)

    int prep_elems = C_ * C_ + C_ * CZ_;
    prep_weights<<<(prep_elems + 255) / 256, 256, 0, stream>>>(W_s, W_z, wts, wtz);
    fused_msg_kernel<<<NSITES / 2, 256, 0, stream>>>(s_i, s_ij, m_ij, z_ij, wts, wtz,
                                                     gamma, beta, out);
}